// Round 7
// baseline (11977.702 us; speedup 1.0000x reference)
//
#include <hip/hip_runtime.h>

typedef unsigned int u32;
typedef unsigned long long u64;

#define N_PTS 65536
#define NB_ 25
#define NSAMP 2622            // ceil(65536/25)
#define NCELL 1000            // 10x10x10 spatial grid
#define CAND_CAP 7900

__device__ __forceinline__ float dist2_exact(float px,float py,float pz,
                                             float qx,float qy,float qz){
  // numpy: ((dx*dx + dy*dy) + dz*dz), f32 round-to-nearest, NO fma contraction
  float dx=__fsub_rn(px,qx), dy=__fsub_rn(py,qy), dz=__fsub_rn(pz,qz);
  return __fadd_rn(__fadd_rn(__fmul_rn(dx,dx),__fmul_rn(dy,dy)),__fmul_rn(dz,dz));
}

// ---------------- K0: SoA transpose + zero cell state ------------------------
__global__ void k_setup(const float* __restrict__ pts, float* __restrict__ xs,
                        float* __restrict__ ys, float* __restrict__ zs,
                        u32* __restrict__ sinds, u32* __restrict__ cnt,
                        u32* __restrict__ fill, u32* __restrict__ amin,
                        u32* __restrict__ amax){
  int i = blockIdx.x*blockDim.x + threadIdx.x;
  if (i < N_PTS){ xs[i]=pts[3*i]; ys[i]=pts[3*i+1]; zs[i]=pts[3*i+2]; }
  if (i < 1024){
    cnt[i]=0u; fill[i]=0u;
    amin[i]=0x7F800000u; amin[1024+i]=0x7F800000u; amin[2048+i]=0x7F800000u;
    amax[i]=0u;          amax[1024+i]=0u;          amax[2048+i]=0u;
  }
  if (i==0) sinds[0]=0u;
}

__device__ __forceinline__ int cell_of(float x,float y,float z){
  int ix = min(9,(int)(x*10.0f)), iy = min(9,(int)(y*10.0f)), iz = min(9,(int)(z*10.0f));
  return ix + 10*iy + 100*iz;
}

// ---------------- K1a: histogram + exact point bounding boxes ----------------
__global__ void k_hist(const float* __restrict__ xs, const float* __restrict__ ys,
                       const float* __restrict__ zs, u32* __restrict__ cnt,
                       u32* __restrict__ amin, u32* __restrict__ amax){
  int i = blockIdx.x*blockDim.x + threadIdx.x;
  if (i >= N_PTS) return;
  float x=xs[i], y=ys[i], z=zs[i];
  int c = cell_of(x,y,z);
  atomicAdd(&cnt[c],1u);
  // coords in [0,1): positive floats -> u32-bit order == float order
  atomicMin(&amin[c],      __float_as_uint(x)); atomicMax(&amax[c],      __float_as_uint(x));
  atomicMin(&amin[1024+c], __float_as_uint(y)); atomicMax(&amax[1024+c], __float_as_uint(y));
  atomicMin(&amin[2048+c], __float_as_uint(z)); atomicMax(&amax[2048+c], __float_as_uint(z));
}

// ---------------- K1b: exclusive prefix sum over cell counts -----------------
__global__ void __launch_bounds__(1024) k_prefix(const u32* __restrict__ cnt,
                                                 u32* __restrict__ base){
  __shared__ u32 s[1024];
  int tid = threadIdx.x;
  u32 x = (tid < NCELL) ? cnt[tid] : 0u;
  s[tid] = x; __syncthreads();
  for (int off=1; off<1024; off<<=1){
    u32 v = (tid >= off) ? s[tid-off] : 0u;
    __syncthreads();
    s[tid] += v;
    __syncthreads();
  }
  if (tid < NCELL) base[tid] = s[tid] - x;
}

// ---------------- K1c: scatter points into sorted cell order -----------------
__global__ void k_scatter(const float* __restrict__ xs, const float* __restrict__ ys,
                          const float* __restrict__ zs, const u32* __restrict__ base,
                          u32* __restrict__ fill, float4* __restrict__ P4,
                          u32* __restrict__ OID){
  int i = blockIdx.x*blockDim.x + threadIdx.x;
  if (i >= N_PTS) return;
  float x=xs[i], y=ys[i], z=zs[i];
  int c = cell_of(x,y,z);
  u32 pos = base[c] + atomicAdd(&fill[c],1u);
  P4[pos] = make_float4(x,y,z,__builtin_huge_valf());
  OID[pos] = (u32)i;
}

// ------ K2: single-block FPS with exact cell screening (zero global sync) ----
__global__ void __launch_bounds__(1024) k_fps1(
    const float* __restrict__ xs, const float* __restrict__ ys,
    const float* __restrict__ zs, const u32* __restrict__ g_cnt,
    const u32* __restrict__ g_base, const u32* __restrict__ g_amin,
    const u32* __restrict__ g_amax, float4* __restrict__ P4,
    const u32* __restrict__ OID, u32* __restrict__ sinds)
{
  __shared__ float s_lox[NCELL], s_hix[NCELL], s_loy[NCELL], s_hiy[NCELL],
                   s_loz[NCELL], s_hiz[NCELL];
  __shared__ u32 s_cnt[NCELL], s_base[NCELL];
  __shared__ u64 s_ckey[NCELL];
  __shared__ u64 s_red[16];
  __shared__ float s_q[3];

  const int tid = threadIdx.x;
  const int lane = tid & 63, w = tid >> 6;   // 16 waves

  for (int i = tid; i < NCELL; i += 1024){
    u32 c0 = g_cnt[i];
    s_cnt[i]=c0; s_base[i]=g_base[i];
    s_lox[i]=__uint_as_float(g_amin[i]);      s_hix[i]=__uint_as_float(g_amax[i]);
    s_loy[i]=__uint_as_float(g_amin[1024+i]); s_hiy[i]=__uint_as_float(g_amax[1024+i]);
    s_loz[i]=__uint_as_float(g_amin[2048+i]); s_hiz[i]=__uint_as_float(g_amax[2048+i]);
    s_ckey[i] = c0 ? 0x7F80000000000000ULL : 0ULL;  // ub=+inf -> scan all first iter
  }
  if (tid==0){ s_q[0]=xs[0]; s_q[1]=ys[0]; s_q[2]=zs[0]; }
  __syncthreads();

  for (int t=0; t<NSAMP-1; ++t){
    const float qx=s_q[0], qy=s_q[1], qz=s_q[2];

    // ---- screen: lane l of wave w owns cell (l<<4)|w ----
    const int c = (lane<<4) | w;
    bool need = false;
    if (c < NCELL && s_cnt[c]){
      float ub = __uint_as_float((u32)(s_ckey[c]>>32));
      float dx = fmaxf(fmaxf(__fsub_rn(s_lox[c],qx), __fsub_rn(qx,s_hix[c])), 0.f);
      float dy = fmaxf(fmaxf(__fsub_rn(s_loy[c],qy), __fsub_rn(qy,s_hiy[c])), 0.f);
      float dz = fmaxf(fmaxf(__fsub_rn(s_loz[c],qz), __fsub_rn(qz,s_hiz[c])), 0.f);
      float lb = __fadd_rn(__fadd_rn(__fmul_rn(dx,dx),__fmul_rn(dy,dy)),__fmul_rn(dz,dz));
      need = lb < ub;       // only then can any mind in the cell change
    }

    // ---- scan flagged cells, whole wave per cell ----
    u64 todo = __ballot(need);
    while (todo){
      int l = __ffsll((unsigned long long)todo) - 1;
      todo &= todo - 1;
      int sc = (l<<4) | w;
      u32 base = s_base[sc], cn = s_cnt[sc];
      u64 mykey = 0ULL;
      for (u32 j = (u32)lane; j < cn; j += 64u){
        float4 v = P4[base + j];
        float d2 = dist2_exact(v.x,v.y,v.z,qx,qy,qz);
        float nm = fminf(v.w, d2);
        if (nm < v.w) ((float*)(P4 + base + j))[3] = nm;   // update mind
        u32 oid = OID[base + j];
        u64 kk = ((u64)__float_as_uint(nm)<<32)
               | ((u64)(oid ^ 0xFFFFu)<<16) | (u64)(base + j);
        if (kk > mykey) mykey = kk;
      }
      #pragma unroll
      for (int off=1; off<64; off<<=1){ u64 o=__shfl_xor(mykey,off,64); if(o>mykey)mykey=o; }
      if (lane==0) s_ckey[sc] = mykey;
    }
    __syncthreads();                    // bar1: all cell keys final

    // ---- block argmax over cached cell keys ----
    u64 kk = (tid < NCELL) ? s_ckey[tid] : 0ULL;
    #pragma unroll
    for (int off=1; off<64; off<<=1){ u64 o=__shfl_xor(kk,off,64); if(o>kk)kk=o; }
    if (lane==0) s_red[w]=kk;
    __syncthreads();                    // bar2
    if (w==0){
      u64 r = (lane<16) ? s_red[lane] : 0ULL;
      #pragma unroll
      for (int off=1; off<16; off<<=1){ u64 o=__shfl_xor(r,off,64); if(o>r)r=o; }
      if (lane==0){
        u32 spos = (u32)(r & 0xFFFFu);
        u32 widx = (((u32)(r>>16)) & 0xFFFFu) ^ 0xFFFFu;
        float4 wp = P4[spos];
        s_q[0]=wp.x; s_q[1]=wp.y; s_q[2]=wp.z;
        sinds[t+1]=widx;
      }
    }
    __syncthreads();                    // bar3
  }
}

// ---------------- K3: ball query + 25-NN (block per sample) ------------------
__global__ void __launch_bounds__(256) k_ballknn(
    const float* __restrict__ xs, const float* __restrict__ ys,
    const float* __restrict__ zs, const u32* __restrict__ sample_inds,
    u32* __restrict__ rad_inds, float* __restrict__ out_pts,
    float* __restrict__ out_cluster)
{
  __shared__ u64 s_list[CAND_CAP];
  __shared__ u64 s_red[4];
  __shared__ u64 s_win;
  __shared__ u32 s_cnt, s_first;
  const int s = blockIdx.x, tid = threadIdx.x;
  const u32 si = sample_inds[s];
  const float qx=xs[si], qy=ys[si], qz=zs[si];
  const float R2 = (float)(0.22*0.22);
  if (tid==0) s_cnt=0u;
  __syncthreads();

  for (int j=tid; j<N_PTS; j+=256){
    float d2 = dist2_exact(xs[j],ys[j],zs[j],qx,qy,qz);
    if (d2 <= R2){
      u32 pos = atomicAdd(&s_cnt,1u);
      if (pos < CAND_CAP) s_list[pos] = ((u64)__float_as_uint(d2)<<32) | (u64)j;
    }
  }
  __syncthreads();
  const int n = (int)min(s_cnt,(u32)CAND_CAP);

  for (int r=0; r<NB_; ++r){
    u64 m = ~0ULL; int mpos = -1;
    for (int p=tid; p<n; p+=256){
      u64 v=s_list[p];
      if (v<m){ m=v; mpos=p; }
    }
    u64 mm=m;
    #pragma unroll
    for (int off=1; off<64; off<<=1){ u64 o=__shfl_xor(mm,off,64); if(o<mm)mm=o; }
    if ((tid&63)==0) s_red[tid>>6]=mm;
    __syncthreads();
    if (tid==0){
      u64 w=s_red[0];
      #pragma unroll
      for (int i=1;i<4;i++) if (s_red[i]<w) w=s_red[i];
      s_win=w;
      if (r==0) s_first=(u32)(w & 0xFFFFFFFFu);
    }
    __syncthreads();
    u64 w = s_win;
    if (m==w && mpos>=0) s_list[mpos]=~0ULL;  // unique key -> exactly one marker
    if (tid==0){
      u32 widx = (r < n) ? (u32)(w & 0xFFFFFFFFu) : s_first; // pad = nearest
      int o = s*NB_ + r;
      rad_inds[o]=widx;
      out_pts[o*3+0]=xs[widx]; out_pts[o*3+1]=ys[widx]; out_pts[o*3+2]=zs[widx];
      out_cluster[o]=(float)s;
    }
    __syncthreads();
  }
}

// ---------------- K4: per-cluster MLP autoencoder ----------------------------
__global__ void __launch_bounds__(256) k_mlp(
    const float* __restrict__ xs, const float* __restrict__ ys,
    const float* __restrict__ zs, const u32* __restrict__ sample_inds,
    const u32* __restrict__ rad_inds,
    const float* __restrict__ ew1, const float* __restrict__ eb1,
    const float* __restrict__ ew2, const float* __restrict__ eb2,
    const float* __restrict__ ew3, const float* __restrict__ eb3,
    const float* __restrict__ dw1, const float* __restrict__ db1,
    const float* __restrict__ dw2, const float* __restrict__ db2,
    const float* __restrict__ dw3, const float* __restrict__ db3,
    float* __restrict__ out_deco)
{
  __shared__ float rel[NB_][3], mid[3];
  __shared__ float h1[NB_][80], h2[NB_][40], h3[NB_][20];
  __shared__ float feat[20], g1[40], g2[80];
  const int s=blockIdx.x, tid=threadIdx.x;

  if (tid==0){ u32 si=sample_inds[s]; mid[0]=xs[si]; mid[1]=ys[si]; mid[2]=zs[si]; }
  __syncthreads();
  if (tid < NB_){
    u32 ri = rad_inds[s*NB_+tid];
    rel[tid][0]=(xs[ri]-mid[0])/0.22f;
    rel[tid][1]=(ys[ri]-mid[1])/0.22f;
    rel[tid][2]=(zs[ri]-mid[2])/0.22f;
  }
  __syncthreads();
  for (int o=tid;o<NB_*80;o+=256){
    int p=o/80, f=o-p*80;
    float a=eb1[f]+rel[p][0]*ew1[0*80+f]+rel[p][1]*ew1[1*80+f]+rel[p][2]*ew1[2*80+f];
    h1[p][f]=fmaxf(a,0.f);
  }
  __syncthreads();
  for (int o=tid;o<NB_*40;o+=256){
    int p=o/40, f=o-p*40;
    float a=eb2[f];
    for (int k=0;k<80;k++) a += h1[p][k]*ew2[k*40+f];
    h2[p][f]=fmaxf(a,0.f);
  }
  __syncthreads();
  for (int o=tid;o<NB_*20;o+=256){
    int p=o/20, f=o-p*20;
    float a=eb3[f];
    for (int k=0;k<40;k++) a += h2[p][k]*ew3[k*20+f];
    h3[p][f]=fmaxf(a,0.f);
  }
  __syncthreads();
  if (tid<20){
    float m=h3[0][tid];
    for (int p=1;p<NB_;p++) m=fmaxf(m,h3[p][tid]);
    feat[tid]=m;
  }
  __syncthreads();
  if (tid<40){
    float a=db1[tid];
    for (int k=0;k<20;k++) a += feat[k]*dw1[k*40+tid];
    g1[tid]=fmaxf(a,0.f);
  }
  __syncthreads();
  if (tid<80){
    float a=db2[tid];
    for (int k=0;k<40;k++) a += g1[k]*dw2[k*80+tid];
    g2[tid]=fmaxf(a,0.f);
  }
  __syncthreads();
  if (tid<NB_*3){
    float a=db3[tid];
    for (int k=0;k<80;k++) a += g2[k]*dw3[k*75+tid];
    int p=tid/3, c=tid-p*3;
    out_deco[(s*NB_+p)*3+c] = a*0.22f + mid[c];
  }
}

// ---------------- launch -----------------------------------------------------
extern "C" void kernel_launch(void* const* d_in, const int* in_sizes, int n_in,
                              void* d_out, int out_size, void* d_ws, size_t ws_size,
                              hipStream_t stream){
  const float* pts=(const float*)d_in[0];
  const float* ew1=(const float*)d_in[1];  const float* eb1=(const float*)d_in[2];
  const float* ew2=(const float*)d_in[3];  const float* eb2=(const float*)d_in[4];
  const float* ew3=(const float*)d_in[5];  const float* eb3=(const float*)d_in[6];
  const float* dw1=(const float*)d_in[7];  const float* db1=(const float*)d_in[8];
  const float* dw2=(const float*)d_in[9];  const float* db2=(const float*)d_in[10];
  const float* dw3=(const float*)d_in[11]; const float* db3=(const float*)d_in[12];

  float* out = (float*)d_out;
  float* out_pts     = out;                 // [65550,3]
  float* out_cluster = out + NSAMP*NB_*3;   // [65550]
  float* out_deco    = out + NSAMP*NB_*4;   // [2622,25,3]

  char* ws = (char*)d_ws;
  float* xs   = (float*)ws;                      // 65536 f
  float* ys   = xs + N_PTS;
  float* zs   = ys + N_PTS;
  u32* sinds  = (u32*)(zs + N_PTS);              // 4096 u32
  u32* rinds  = sinds + 4096;                    // 65552 u32
  u32* cnt    = rinds + 65552;                   // 1024
  u32* fill   = cnt + 1024;                      // 1024
  u32* cbase  = fill + 1024;                     // 1024
  u32* amin   = cbase + 1024;                    // 3*1024
  u32* amax   = amin + 3*1024;                   // 3*1024
  u32* OID    = amax + 3*1024;                   // 65536
  float4* P4  = (float4*)(OID + N_PTS);          // 65536 float4 (16B-aligned)

  k_setup  <<<(N_PTS+255)/256, 256, 0, stream>>>(pts, xs, ys, zs, sinds, cnt, fill, amin, amax);
  k_hist   <<<(N_PTS+255)/256, 256, 0, stream>>>(xs, ys, zs, cnt, amin, amax);
  k_prefix <<<1, 1024, 0, stream>>>(cnt, cbase);
  k_scatter<<<(N_PTS+255)/256, 256, 0, stream>>>(xs, ys, zs, cbase, fill, P4, OID);
  k_fps1   <<<1, 1024, 0, stream>>>(xs, ys, zs, cnt, cbase, amin, amax, P4, OID, sinds);
  k_ballknn<<<NSAMP, 256, 0, stream>>>(xs, ys, zs, sinds, rinds, out_pts, out_cluster);
  k_mlp    <<<NSAMP, 256, 0, stream>>>(xs, ys, zs, sinds, rinds,
                                       ew1,eb1,ew2,eb2,ew3,eb3,
                                       dw1,db1,dw2,db2,dw3,db3, out_deco);
}

// Round 8
// 8795.782 us; speedup vs baseline: 1.3618x; 1.3618x over previous
//
#include <hip/hip_runtime.h>

typedef unsigned int u32;
typedef unsigned long long u64;

#define N_PTS 65536
#define NB_ 25
#define NSAMP 2622            // ceil(65536/25)
#define NCELL 1000            // 10x10x10 spatial grid
#define KCAP 4096             // ball candidates cap (E~2920, +20σ safe)

__device__ __forceinline__ float dist2_exact(float px,float py,float pz,
                                             float qx,float qy,float qz){
  // numpy: ((dx*dx + dy*dy) + dz*dz), f32 round-to-nearest, NO fma contraction
  float dx=__fsub_rn(px,qx), dy=__fsub_rn(py,qy), dz=__fsub_rn(pz,qz);
  return __fadd_rn(__fadd_rn(__fmul_rn(dx,dx),__fmul_rn(dy,dy)),__fmul_rn(dz,dz));
}

__device__ __forceinline__ int cell_of(float x,float y,float z){
  int ix = min(9,(int)(x*10.0f)), iy = min(9,(int)(y*10.0f)), iz = min(9,(int)(z*10.0f));
  return ix + 10*iy + 100*iz;
}

// ---------------- K0: SoA transpose + zero cell state ------------------------
__global__ void k_setup(const float* __restrict__ pts, float* __restrict__ xs,
                        float* __restrict__ ys, float* __restrict__ zs,
                        u32* __restrict__ sinds, u32* __restrict__ cnt,
                        u32* __restrict__ fill, u32* __restrict__ amin,
                        u32* __restrict__ amax){
  int i = blockIdx.x*blockDim.x + threadIdx.x;
  if (i < N_PTS){ xs[i]=pts[3*i]; ys[i]=pts[3*i+1]; zs[i]=pts[3*i+2]; }
  if (i < 1024){
    cnt[i]=0u; fill[i]=0u;
    amin[i]=0x7F800000u; amin[1024+i]=0x7F800000u; amin[2048+i]=0x7F800000u;
    amax[i]=0u;          amax[1024+i]=0u;          amax[2048+i]=0u;
  }
  if (i==0) sinds[0]=0u;
}

// ---------------- K1a: histogram + exact point bounding boxes ----------------
__global__ void k_hist(const float* __restrict__ xs, const float* __restrict__ ys,
                       const float* __restrict__ zs, u32* __restrict__ cnt,
                       u32* __restrict__ amin, u32* __restrict__ amax){
  int i = blockIdx.x*blockDim.x + threadIdx.x;
  if (i >= N_PTS) return;
  float x=xs[i], y=ys[i], z=zs[i];
  int c = cell_of(x,y,z);
  atomicAdd(&cnt[c],1u);
  // coords in [0,1): positive floats -> u32-bit order == float order
  atomicMin(&amin[c],      __float_as_uint(x)); atomicMax(&amax[c],      __float_as_uint(x));
  atomicMin(&amin[1024+c], __float_as_uint(y)); atomicMax(&amax[1024+c], __float_as_uint(y));
  atomicMin(&amin[2048+c], __float_as_uint(z)); atomicMax(&amax[2048+c], __float_as_uint(z));
}

// ---------------- K1b: exclusive prefix sum over cell counts -----------------
__global__ void __launch_bounds__(1024) k_prefix(const u32* __restrict__ cnt,
                                                 u32* __restrict__ base){
  __shared__ u32 s[1024];
  int tid = threadIdx.x;
  u32 x = (tid < NCELL) ? cnt[tid] : 0u;
  s[tid] = x; __syncthreads();
  for (int off=1; off<1024; off<<=1){
    u32 v = (tid >= off) ? s[tid-off] : 0u;
    __syncthreads();
    s[tid] += v;
    __syncthreads();
  }
  if (tid < NCELL) base[tid] = s[tid] - x;
}

// ---------------- K1c: scatter points into sorted cell order -----------------
__global__ void k_scatter(const float* __restrict__ xs, const float* __restrict__ ys,
                          const float* __restrict__ zs, const u32* __restrict__ base,
                          u32* __restrict__ fill, float4* __restrict__ P4,
                          u32* __restrict__ OID){
  int i = blockIdx.x*blockDim.x + threadIdx.x;
  if (i >= N_PTS) return;
  float x=xs[i], y=ys[i], z=zs[i];
  int c = cell_of(x,y,z);
  u32 pos = base[c] + atomicAdd(&fill[c],1u);
  P4[pos] = make_float4(x,y,z,__builtin_huge_valf());
  OID[pos] = (u32)i;
}

// ------ K2: single-block FPS, reg-cached cells + worklist + pipelined scan ---
__global__ void __launch_bounds__(1024) k_fps1(
    const float* __restrict__ xs, const float* __restrict__ ys,
    const float* __restrict__ zs, const u32* __restrict__ g_cnt,
    const u32* __restrict__ g_base, const u32* __restrict__ g_amin,
    const u32* __restrict__ g_amax, float4* __restrict__ P4,
    const u32* __restrict__ OID, u32* __restrict__ sinds)
{
  __shared__ u64 s_ckey[NCELL];
  __shared__ float s_cwx[NCELL], s_cwy[NCELL], s_cwz[NCELL];
  __shared__ u32 s_base[NCELL], s_cnt[NCELL];
  __shared__ u32 s_work[NCELL];
  __shared__ u64 s_red[16];
  __shared__ u32 s_redc[16];
  __shared__ float s_q[3];
  __shared__ u32 s_wcnt;

  const int tid = threadIdx.x;
  const int lane = tid & 63, wv = tid >> 6;   // 16 waves

  // per-thread registers: this thread's cell state (cell id == tid)
  float r_lox=0.f,r_hix=0.f,r_loy=0.f,r_hiy=0.f,r_loz=0.f,r_hiz=0.f;
  u32 r_cnt=0u;
  if (tid < NCELL){
    r_cnt = g_cnt[tid];
    s_cnt[tid]=r_cnt; s_base[tid]=g_base[tid];
    r_lox=__uint_as_float(g_amin[tid]);      r_hix=__uint_as_float(g_amax[tid]);
    r_loy=__uint_as_float(g_amin[1024+tid]); r_hiy=__uint_as_float(g_amax[1024+tid]);
    r_loz=__uint_as_float(g_amin[2048+tid]); r_hiz=__uint_as_float(g_amax[2048+tid]);
    s_ckey[tid] = r_cnt ? 0x7F80000000000000ULL : 0ULL;  // ub=+inf initially
  }
  if (tid==0){ s_q[0]=xs[0]; s_q[1]=ys[0]; s_q[2]=zs[0]; s_wcnt=0u; }
  __syncthreads();

  for (int t=0; t<NSAMP-1; ++t){
    const float qx=s_q[0], qy=s_q[1], qz=s_q[2];

    // ---- A: screen (registers only) + compact into worklist + reset keys ----
    bool flag=false;
    if (r_cnt){
      float ub = __uint_as_float((u32)(s_ckey[tid]>>32));
      float dx = fmaxf(fmaxf(__fsub_rn(r_lox,qx), __fsub_rn(qx,r_hix)), 0.f);
      float dy = fmaxf(fmaxf(__fsub_rn(r_loy,qy), __fsub_rn(qy,r_hiy)), 0.f);
      float dz = fmaxf(fmaxf(__fsub_rn(r_loz,qz), __fsub_rn(qz,r_hiz)), 0.f);
      float lb = __fadd_rn(__fadd_rn(__fmul_rn(dx,dx),__fmul_rn(dy,dy)),__fmul_rn(dz,dz));
      flag = lb < ub;         // rounding-monotone: lb <= true d2 of every cell point
    }
    u64 mball = __ballot(flag);
    u32 pre = __popcll(mball & ((1ull<<lane)-1ull));
    u32 tot = __popcll(mball);
    u32 woff = 0u;
    if (lane==0 && tot) woff = atomicAdd(&s_wcnt, tot);
    woff = __shfl(woff, 0, 64);
    if (flag){ s_work[woff+pre] = (u32)tid; s_ckey[tid]=0ULL; }
    __syncthreads();                               // bar1
    const int nwork = (int)s_wcnt;

    // ---- B: pipelined scan of worklist (wave e%16 handles entry e) ----
    {
      int e = wv;
      if (e < nwork){
        int cc; u32 cb, cn;
        float4 a0=make_float4(0,0,0,0), a1=a0, a2=a0; u32 o0=0,o1=0,o2=0;
        cc=(int)s_work[e]; cb=s_base[cc]; cn=s_cnt[cc];
        { u32 j=cb+(u32)lane;
          if ((u32)lane     < cn){ a0=P4[j];     o0=OID[j];     }
          if ((u32)lane+64u < cn){ a1=P4[j+64];  o1=OID[j+64];  }
          if ((u32)lane+128u< cn){ a2=P4[j+128]; o2=OID[j+128]; } }
        for(;;){
          const int e2 = e+16;
          const bool more = (e2 < nwork);
          int c2=0; u32 b2=0,n2=0;
          float4 g0=make_float4(0,0,0,0), g1=g0, g2=g0; u32 p0=0,p1=0,p2=0;
          if (more){
            c2=(int)s_work[e2]; b2=s_base[c2]; n2=s_cnt[c2];
            u32 j=b2+(u32)lane;
            if ((u32)lane     < n2){ g0=P4[j];     p0=OID[j];     }
            if ((u32)lane+64u < n2){ g1=P4[j+64];  p1=OID[j+64];  }
            if ((u32)lane+128u< n2){ g2=P4[j+128]; p2=OID[j+128]; }
          }
          // compute current entry
          u64 key=0ULL; float wx=0.f,wy=0.f,wz=0.f;
          #define TRIP(J,V,O) do{ u32 j_=(J); if (j_<cn){ \
              float d2_=dist2_exact((V).x,(V).y,(V).z,qx,qy,qz); \
              float nm_=fminf((V).w,d2_); \
              if (nm_<(V).w) ((float*)(P4+cb+j_))[3]=nm_; \
              u64 k_=((u64)__float_as_uint(nm_)<<32) \
                   |((u64)(((O)^0xFFFFu)&0xFFFFu)<<16)|(u64)(cb+j_); \
              if (k_>key){key=k_; wx=(V).x; wy=(V).y; wz=(V).z;} } }while(0)
          TRIP((u32)lane,      a0, o0);
          TRIP((u32)lane+64u,  a1, o1);
          TRIP((u32)lane+128u, a2, o2);
          for (u32 j=(u32)lane+192u; j<cn; j+=64u){   // safety tail (cn>192: ~never)
            float4 v=P4[cb+j]; u32 o=OID[cb+j];
            TRIP(j, v, o);
          }
          #undef TRIP
          u64 wk=key;
          #pragma unroll
          for (int off=1; off<64; off<<=1){ u64 o=__shfl_xor(wk,off,64); if(o>wk)wk=o; }
          if (key==wk && wk){   // unique lane (keys unique by pos)
            s_ckey[cc]=wk; s_cwx[cc]=wx; s_cwy[cc]=wy; s_cwz[cc]=wz;
          }
          if (!more) break;
          e=e2; cc=c2; cb=b2; cn=n2;
          a0=g0; a1=g1; a2=g2; o0=p0; o1=p1; o2=p2;
        }
      }
    }
    __syncthreads();                               // bar2

    // ---- C: block argmax over cached cell keys (track winning cell) ----
    u64 kk = (tid<NCELL) ? s_ckey[tid] : 0ULL;
    u32 cid = (u32)tid;
    #pragma unroll
    for (int off=1; off<64; off<<=1){
      u64 ok=__shfl_xor(kk,off,64); u32 oc=__shfl_xor(cid,off,64);
      if (ok>kk){ kk=ok; cid=oc; }
    }
    if (lane==0){ s_red[wv]=kk; s_redc[wv]=cid; }
    __syncthreads();                               // bar3
    if (tid==0){
      u64 bk=s_red[0]; u32 bc=s_redc[0];
      #pragma unroll
      for (int i=1;i<16;i++) if (s_red[i]>bk){ bk=s_red[i]; bc=s_redc[i]; }
      s_q[0]=s_cwx[bc]; s_q[1]=s_cwy[bc]; s_q[2]=s_cwz[bc];
      sinds[t+1] = (((u32)(bk>>16))&0xFFFFu)^0xFFFFu;
      s_wcnt = 0u;
    }
    __syncthreads();                               // bar4
  }
}

// ---------------- K3: grid-accelerated ball query + 25-NN --------------------
__global__ void __launch_bounds__(256) k_ballknn(
    const float4* __restrict__ P4, const u32* __restrict__ OID,
    const u32* __restrict__ g_cnt, const u32* __restrict__ g_base,
    const float* __restrict__ xs, const float* __restrict__ ys,
    const float* __restrict__ zs, const u32* __restrict__ sample_inds,
    u32* __restrict__ rad_inds, float* __restrict__ out_pts,
    float* __restrict__ out_cluster)
{
  __shared__ u64 s_list[KCAP];
  __shared__ u64 s_red[4];
  __shared__ u64 s_win;
  __shared__ u32 s_cnt2, s_first;
  const int s = blockIdx.x, tid = threadIdx.x;
  const int lane = tid & 63, wv = tid >> 6;
  const u32 si = sample_inds[s];
  const float qx=xs[si], qy=ys[si], qz=zs[si];
  const float R2 = (float)(0.22*0.22);
  const float RP = 0.2200002f;              // epsilon-padded box (conservative)
  if (tid==0) s_cnt2=0u;
  __syncthreads();

  int ix0=max(0,(int)floorf((qx-RP)*10.f)), ix1=min(9,(int)floorf((qx+RP)*10.f));
  int iy0=max(0,(int)floorf((qy-RP)*10.f)), iy1=min(9,(int)floorf((qy+RP)*10.f));
  int iz0=max(0,(int)floorf((qz-RP)*10.f)), iz1=min(9,(int)floorf((qz+RP)*10.f));
  int nx=ix1-ix0+1, ny=iy1-iy0+1, nz=iz1-iz0+1;
  int ncl=nx*ny*nz;

  for (int ii=wv; ii<ncl; ii+=4){            // wave per cell
    int cx=ix0+ii%nx, cy=iy0+(ii/nx)%ny, cz=iz0+ii/(nx*ny);
    float lx=cx*0.1f, hx=lx+0.1f, ly=cy*0.1f, hy=ly+0.1f, lz=cz*0.1f, hz=lz+0.1f;
    float ddx=fmaxf(fmaxf(lx-qx,qx-hx),0.f);
    float ddy=fmaxf(fmaxf(ly-qy,qy-hy),0.f);
    float ddz=fmaxf(fmaxf(lz-qz,qz-hz),0.f);
    float lb=ddx*ddx+ddy*ddy+ddz*ddz;
    if (lb > R2*1.002f) continue;            // conservative cell skip
    int c = cx+10*cy+100*cz;
    u32 cb=g_base[c], cn=g_cnt[c];
    for (u32 j=(u32)lane; j<cn; j+=64u){
      float4 v = P4[cb+j];
      float d2 = dist2_exact(v.x,v.y,v.z,qx,qy,qz);
      bool in = (d2 <= R2);                  // exact membership test
      u64 mk = __ballot(in);
      u32 off=0u;
      if (lane==0 && mk) off = atomicAdd(&s_cnt2,(u32)__popcll(mk));
      off = __shfl(off,0,64);
      if (in){
        u32 o = OID[cb+j];
        s_list[off+__popcll(mk&((1ull<<lane)-1ull))] =
            ((u64)__float_as_uint(d2)<<32) | (u64)o;   // key=(d2, orig idx)
      }
    }
  }
  __syncthreads();
  const int n = (int)min(s_cnt2,(u32)KCAP);

  for (int r=0; r<NB_; ++r){
    u64 m = ~0ULL; int mpos = -1;
    for (int p=tid; p<n; p+=256){
      u64 v=s_list[p];
      if (v<m){ m=v; mpos=p; }
    }
    u64 mm=m;
    #pragma unroll
    for (int off=1; off<64; off<<=1){ u64 o=__shfl_xor(mm,off,64); if(o<mm)mm=o; }
    if ((tid&63)==0) s_red[tid>>6]=mm;
    __syncthreads();
    if (tid==0){
      u64 w=s_red[0];
      #pragma unroll
      for (int i=1;i<4;i++) if (s_red[i]<w) w=s_red[i];
      s_win=w;
      if (r==0) s_first=(u32)(w & 0xFFFFFFFFu);
    }
    __syncthreads();
    u64 w = s_win;
    if (m==w && mpos>=0) s_list[mpos]=~0ULL;  // unique key -> one marker
    if (tid==0){
      u32 widx = (r < n) ? (u32)(w & 0xFFFFFFFFu) : s_first; // pad = nearest
      int o = s*NB_ + r;
      rad_inds[o]=widx;
      out_pts[o*3+0]=xs[widx]; out_pts[o*3+1]=ys[widx]; out_pts[o*3+2]=zs[widx];
      out_cluster[o]=(float)s;
    }
    __syncthreads();
  }
}

// ---------------- K4: per-cluster MLP autoencoder ----------------------------
__global__ void __launch_bounds__(256) k_mlp(
    const float* __restrict__ xs, const float* __restrict__ ys,
    const float* __restrict__ zs, const u32* __restrict__ sample_inds,
    const u32* __restrict__ rad_inds,
    const float* __restrict__ ew1, const float* __restrict__ eb1,
    const float* __restrict__ ew2, const float* __restrict__ eb2,
    const float* __restrict__ ew3, const float* __restrict__ eb3,
    const float* __restrict__ dw1, const float* __restrict__ db1,
    const float* __restrict__ dw2, const float* __restrict__ db2,
    const float* __restrict__ dw3, const float* __restrict__ db3,
    float* __restrict__ out_deco)
{
  __shared__ float rel[NB_][3], mid[3];
  __shared__ float h1[NB_][80], h2[NB_][40], h3[NB_][20];
  __shared__ float feat[20], g1[40], g2[80];
  const int s=blockIdx.x, tid=threadIdx.x;

  if (tid==0){ u32 si=sample_inds[s]; mid[0]=xs[si]; mid[1]=ys[si]; mid[2]=zs[si]; }
  __syncthreads();
  if (tid < NB_){
    u32 ri = rad_inds[s*NB_+tid];
    rel[tid][0]=(xs[ri]-mid[0])/0.22f;
    rel[tid][1]=(ys[ri]-mid[1])/0.22f;
    rel[tid][2]=(zs[ri]-mid[2])/0.22f;
  }
  __syncthreads();
  for (int o=tid;o<NB_*80;o+=256){
    int p=o/80, f=o-p*80;
    float a=eb1[f]+rel[p][0]*ew1[0*80+f]+rel[p][1]*ew1[1*80+f]+rel[p][2]*ew1[2*80+f];
    h1[p][f]=fmaxf(a,0.f);
  }
  __syncthreads();
  for (int o=tid;o<NB_*40;o+=256){
    int p=o/40, f=o-p*40;
    float a=eb2[f];
    for (int k=0;k<80;k++) a += h1[p][k]*ew2[k*40+f];
    h2[p][f]=fmaxf(a,0.f);
  }
  __syncthreads();
  for (int o=tid;o<NB_*20;o+=256){
    int p=o/20, f=o-p*20;
    float a=eb3[f];
    for (int k=0;k<40;k++) a += h2[p][k]*ew3[k*20+f];
    h3[p][f]=fmaxf(a,0.f);
  }
  __syncthreads();
  if (tid<20){
    float m=h3[0][tid];
    for (int p=1;p<NB_;p++) m=fmaxf(m,h3[p][tid]);
    feat[tid]=m;
  }
  __syncthreads();
  if (tid<40){
    float a=db1[tid];
    for (int k=0;k<20;k++) a += feat[k]*dw1[k*40+tid];
    g1[tid]=fmaxf(a,0.f);
  }
  __syncthreads();
  if (tid<80){
    float a=db2[tid];
    for (int k=0;k<40;k++) a += g1[k]*dw2[k*80+tid];
    g2[tid]=fmaxf(a,0.f);
  }
  __syncthreads();
  if (tid<NB_*3){
    float a=db3[tid];
    for (int k=0;k<80;k++) a += g2[k]*dw3[k*75+tid];
    int p=tid/3, c=tid-p*3;
    out_deco[(s*NB_+p)*3+c] = a*0.22f + mid[c];
  }
}

// ---------------- launch -----------------------------------------------------
extern "C" void kernel_launch(void* const* d_in, const int* in_sizes, int n_in,
                              void* d_out, int out_size, void* d_ws, size_t ws_size,
                              hipStream_t stream){
  const float* pts=(const float*)d_in[0];
  const float* ew1=(const float*)d_in[1];  const float* eb1=(const float*)d_in[2];
  const float* ew2=(const float*)d_in[3];  const float* eb2=(const float*)d_in[4];
  const float* ew3=(const float*)d_in[5];  const float* eb3=(const float*)d_in[6];
  const float* dw1=(const float*)d_in[7];  const float* db1=(const float*)d_in[8];
  const float* dw2=(const float*)d_in[9];  const float* db2=(const float*)d_in[10];
  const float* dw3=(const float*)d_in[11]; const float* db3=(const float*)d_in[12];

  float* out = (float*)d_out;
  float* out_pts     = out;                 // [65550,3]
  float* out_cluster = out + NSAMP*NB_*3;   // [65550]
  float* out_deco    = out + NSAMP*NB_*4;   // [2622,25,3]

  char* ws = (char*)d_ws;
  float* xs   = (float*)ws;                      // 65536 f
  float* ys   = xs + N_PTS;
  float* zs   = ys + N_PTS;
  u32* sinds  = (u32*)(zs + N_PTS);              // 4096 u32
  u32* rinds  = sinds + 4096;                    // 65552 u32
  u32* cnt    = rinds + 65552;                   // 1024
  u32* fill   = cnt + 1024;                      // 1024
  u32* cbase  = fill + 1024;                     // 1024
  u32* amin   = cbase + 1024;                    // 3*1024
  u32* amax   = amin + 3*1024;                   // 3*1024
  u32* OID    = amax + 3*1024;                   // 65536
  float4* P4  = (float4*)(OID + N_PTS);          // 65536 float4 (16B-aligned)

  k_setup  <<<(N_PTS+255)/256, 256, 0, stream>>>(pts, xs, ys, zs, sinds, cnt, fill, amin, amax);
  k_hist   <<<(N_PTS+255)/256, 256, 0, stream>>>(xs, ys, zs, cnt, amin, amax);
  k_prefix <<<1, 1024, 0, stream>>>(cnt, cbase);
  k_scatter<<<(N_PTS+255)/256, 256, 0, stream>>>(xs, ys, zs, cbase, fill, P4, OID);
  k_fps1   <<<1, 1024, 0, stream>>>(xs, ys, zs, cnt, cbase, amin, amax, P4, OID, sinds);
  k_ballknn<<<NSAMP, 256, 0, stream>>>(P4, OID, cnt, cbase, xs, ys, zs, sinds,
                                       rinds, out_pts, out_cluster);
  k_mlp    <<<NSAMP, 256, 0, stream>>>(xs, ys, zs, sinds, rinds,
                                       ew1,eb1,ew2,eb2,ew3,eb3,
                                       dw1,db1,dw2,db2,dw3,db3, out_deco);
}